// Round 9
// baseline (191.508 us; speedup 1.0000x reference)
//
#include <hip/hip_runtime.h>
#include <cstddef>
#include <cstdint>

// LocalAttention MI355X round 17.
//   cvt_all:   fp32 -> bf16 + 128B zero pad (unchanged).
//   gemm_qkv/gemm_out: BK=64 MFMA core now DOUBLE-BUFFERED 2-phase (T3-min):
//              stage(k+1) issued BEFORE compute(k) into the other 32 KB
//              half; ONE __syncthreads per K-step (drains the just-issued
//              DMA after compute covered its latency). 64 KB LDS ->
//              2 blocks/CU. r8 analysis: 1-phase serialized ~500cy DMA
//              latency with ~770cy compute every K-step; floors say ~16 us
//              vs ~40 observed for gemm_qkv.
//   attn_q4:   async-DMA fill version (unchanged from r16: attn < 41 us,
//              dropped out of top-5 behind the harness's 41 us ws-poison
//              fill; total A/B vs r5 gives ~-8 us).
// ws: 86 MB + 128 B of 256 MiB.

namespace {

typedef short s16x8 __attribute__((ext_vector_type(8)));
typedef unsigned short u16x8 __attribute__((ext_vector_type(8)));
typedef float f32x4 __attribute__((ext_vector_type(4)));

constexpr int kHeads = 8;
constexpr int kN = 4096;          // pixels per image
constexpr float kScale = 0.125f;  // 64^-0.5

__device__ inline float blo(unsigned u) {
  return __uint_as_float(u << 16);
}
__device__ inline float bhi(unsigned u) {
  return __uint_as_float(u & 0xffff0000u);
}
__device__ inline unsigned short f2b(float x) {
  unsigned u = __float_as_uint(x);  // RNE
  return (unsigned short)((u + 0x7fffu + ((u >> 16) & 1u)) >> 16);
}

// d += dot2(packed bf16 a, packed bf16 b), f32 accumulate (CDNA4 VOP3P)
__device__ __forceinline__ float dot2bf(float d, unsigned a, unsigned b) {
  asm("v_dot2_f32_bf16 %0, %1, %2, %0" : "+v"(d) : "v"(a), "v"(b));
  return d;
}

// async global->LDS, 16 B per lane; LDS dest = wave-uniform base + lane*16
__device__ __forceinline__ void g2l16(const unsigned short* g,
                                      unsigned short* l) {
  __builtin_amdgcn_global_load_lds(
      (const __attribute__((address_space(1))) void*)g,
      (__attribute__((address_space(3))) void*)l, 16, 0, 0);
}

// ---------------- fp32 -> bf16 for all three tensors -------------------------
__global__ __launch_bounds__(256) void cvt_all(
    const float* __restrict__ wq, const float* __restrict__ wo,
    const float* __restrict__ x, unsigned short* __restrict__ wqb,
    unsigned short* __restrict__ wob, unsigned short* __restrict__ xb,
    unsigned short* __restrict__ zp) {
  const int i = blockIdx.x * 256 + threadIdx.x;  // 0..1179647
  if (i < 16) ((unsigned long long*)zp)[i] = 0ull;  // 128B zero pad for attn
  const float* src;
  unsigned short* dst;
  int off;
  if (i < 98304) {
    src = wq; dst = wqb; off = i;
  } else if (i < 131072) {
    src = wo; dst = wob; off = i - 98304;
  } else {
    src = x; dst = xb; off = i - 131072;
  }
  const float4 a = ((const float4*)src)[off * 2];
  const float4 b = ((const float4*)src)[off * 2 + 1];
  u16x8 o;
  o[0] = f2b(a.x); o[1] = f2b(a.y); o[2] = f2b(a.z); o[3] = f2b(a.w);
  o[4] = f2b(b.x); o[5] = f2b(b.y); o[6] = f2b(b.z); o[7] = f2b(b.w);
  *(u16x8*)(dst + (size_t)off * 8) = o;
}

// ---------------- MFMA GEMM core: 128x128 tile, K=512, BK=64, dbuf ----------
// XOR-swizzled staging: lane stages logical k-seg (lane&7)^(row&7) so the
// g2l16-forced layout (base + lane*16B) yields bank-spread ds_read_b128.
// 2-phase: stage(k+1) into buf^1 BEFORE compute(k) on buf; one barrier/step.
__device__ __forceinline__ void stage64(const unsigned short* __restrict__ A,
                                        const unsigned short* __restrict__ W,
                                        int m0, int n0, int k0, int wv,
                                        int rsub, int slog,
                                        unsigned short* As,
                                        unsigned short* Bs) {
#pragma unroll
  for (int it = 0; it < 4; ++it) {
    const int g = wv * 4 + it;  // 0..15 -> 8-row group
    const int row = g * 8 + rsub;
    g2l16(A + (size_t)(m0 + row) * 512 + k0 + slog * 8, As + g * 512);
    g2l16(W + (size_t)(n0 + row) * 512 + k0 + slog * 8, Bs + g * 512);
  }
}

__device__ __forceinline__ void mfma_512(const unsigned short* __restrict__ A,
                                         const unsigned short* __restrict__ W,
                                         int m0, int n0, int tid,
                                         unsigned short* As, unsigned short* Bs,
                                         f32x4 (&acc)[4][4]) {
  const int lane = tid & 63;
  const int wv = tid >> 6;
  const int wm = wv & 1, wn = wv >> 1;
  const int rsub = lane >> 3;              // row within 8-row group
  const int slog = (lane & 7) ^ rsub;      // logical k-seg this lane stages
#pragma unroll
  for (int i = 0; i < 4; ++i)
#pragma unroll
    for (int j = 0; j < 4; ++j) acc[i][j] = f32x4{0.f, 0.f, 0.f, 0.f};

  stage64(A, W, m0, n0, 0, wv, rsub, slog, As, Bs);
  __syncthreads();
  int buf = 0;
  for (int k = 0; k < 8; ++k) {
    if (k < 7)  // issue next-tile DMA early; latency hides under compute(k)
      stage64(A, W, m0, n0, (k + 1) * 64, wv, rsub, slog,
              As + (buf ^ 1) * 8192, Bs + (buf ^ 1) * 8192);
    const unsigned short* as = As + buf * 8192;
    const unsigned short* bs = Bs + buf * 8192;
#pragma unroll
    for (int kh = 0; kh < 2; ++kh) {
      s16x8 af[4], bf[4];
      const int q = kh * 4 + (lane >> 4);  // logical k-seg wanted
#pragma unroll
      for (int i = 0; i < 4; ++i) {
        const int Ra = wm * 64 + i * 16 + (lane & 15);
        af[i] = *(const s16x8*)&as[Ra * 64 + ((q ^ (Ra & 7)) * 8)];
        const int Rb = wn * 64 + i * 16 + (lane & 15);
        bf[i] = *(const s16x8*)&bs[Rb * 64 + ((q ^ (Rb & 7)) * 8)];
      }
#pragma unroll
      for (int i = 0; i < 4; ++i)
#pragma unroll
        for (int j = 0; j < 4; ++j)
          acc[i][j] = __builtin_amdgcn_mfma_f32_16x16x32_bf16(
              af[i], bf[j], acc[i][j], 0, 0, 0);
    }
    __syncthreads();  // drains stage(k+1) DMA + all waves done reading buf
    buf ^= 1;
  }
}

// ---------------- QKV projection GEMM, full M=16384 --------------------------
__global__ __launch_bounds__(256, 3) void gemm_qkv(
    const unsigned short* __restrict__ A, const unsigned short* __restrict__ W,
    unsigned short* __restrict__ Qb, unsigned short* __restrict__ Kb,
    unsigned short* __restrict__ Vb) {
  __shared__ unsigned short As[16384], Bs[16384];  // 32 KB each (dbuf)
  const int tid = threadIdx.x;
  const int id = blockIdx.x;
  const int xcd = id & 7;
  const int j = id >> 3;            // 0..191
  const int by = xcd * 16 + j / 12; // 0..127
  const int bx = j % 12;
  f32x4 acc[4][4];
  mfma_512(A, W, by * 128, bx * 128, tid, As, Bs, acc);

  const int lane = tid & 63;
  const int wv = tid >> 6;
  const int wm = wv & 1, wn = wv >> 1;
  const int cn = bx * 128 + wn * 64;  // 64-aligned => head/qkv wave-uniform
  unsigned short* dst = (cn < 512) ? Qb : (cn < 1024 ? Kb : Vb);
  const int head = (cn >> 6) & 7;
  const int colb = lane & 15;
#pragma unroll
  for (int mi = 0; mi < 4; ++mi) {
#pragma unroll
    for (int r = 0; r < 4; ++r) {
      const int m = by * 128 + wm * 64 + mi * 16 + (lane >> 4) * 4 + r;
      const int b = m >> 12;
      const int p = m & 4095;
      unsigned short* o =
          dst + ((size_t)(b * kHeads + head) * kN + p) * 64 + colb;
#pragma unroll
      for (int ni = 0; ni < 4; ++ni) o[ni * 16] = f2b(acc[mi][ni][r]);
    }
  }
}

// ---------------- out-projection GEMM ----------------------------------------
__global__ __launch_bounds__(256, 3) void gemm_out(
    const unsigned short* __restrict__ A, const unsigned short* __restrict__ W,
    const float* __restrict__ bias, float* __restrict__ out) {
  __shared__ unsigned short As[16384], Bs[16384];  // 32 KB each (dbuf)
  const int tid = threadIdx.x;
  const int id = blockIdx.x;
  const int xcd = id & 7;
  const int j = id >> 3;               // 0..63
  const int by = xcd * 16 + (j >> 2);  // 0..127
  const int bx = j & 3;
  f32x4 acc[4][4];
  mfma_512(A, W, by * 128, bx * 128, tid, As, Bs, acc);

  const int lane = tid & 63;
  const int wv = tid >> 6;
  const int wm = wv & 1, wn = wv >> 1;
  float bvr[4];
#pragma unroll
  for (int ni = 0; ni < 4; ++ni)
    bvr[ni] = bias[bx * 128 + wn * 64 + ni * 16 + (lane & 15)];
#pragma unroll
  for (int mi = 0; mi < 4; ++mi) {
#pragma unroll
    for (int r = 0; r < 4; ++r) {
      const int m = by * 128 + wm * 64 + mi * 16 + (lane >> 4) * 4 + r;
      float* o = out + (size_t)m * 512 + bx * 128 + wn * 64 + (lane & 15);
#pragma unroll
      for (int ni = 0; ni < 4; ++ni) o[ni * 16] = acc[mi][ni][r] + bvr[ni];
    }
  }
}

// ---------------- fused local attention, async-DMA fill ----------------------
// 256 threads/block, 8x8 pixel tile, quad-split (4 threads/pixel x 16 dims).
// H0 = K halo, H1 = V halo, 144 rows x 64 shorts each (36.86 KB total).
// Both fills are global_load_lds salvos issued at kernel start. Swizzle on
// the GLOBAL source (lane fetches chunk (lane&7)^(row&7)), LDS linear.
// OOB rows pull from a zeroed 128B ws slab. vmcnt(4): K drained, V in
// flight; QK + softmax overlap the V DMA; vmcnt(0)+barrier before PV.
__global__ __launch_bounds__(256) void attn_q4(
    const unsigned short* __restrict__ Q, const unsigned short* __restrict__ K,
    const unsigned short* __restrict__ V, const unsigned short* __restrict__ Zp,
    unsigned short* __restrict__ AO) {
  __shared__ unsigned short H[2 * 144 * 64];  // 36.86 KB: [0]=K, [9216]=V
  const int tid = threadIdx.x;  // 0..255
  const int id = blockIdx.x;    // 0..2047
  const int wv = tid >> 6;
  // XCD-clustered mapping: 4 heads' K/V (2 MB) per XCD L2.
  const int xcd = id & 7;
  const int k8 = id >> 3;              // 0..255
  const int bh = xcd * 4 + (k8 >> 6);  // 0..31
  const int tile = k8 & 63;            // 0..63
  const int ty0 = (tile >> 3) * 8, tx0 = (tile & 7) * 8;
  const size_t base = (size_t)bh * kN;
  const int pix = tid >> 2;  // 0..63
  const int sub = tid & 3;   // which 16-dim quarter
  const int pyl = pix >> 3, pxl = pix & 7;
  const int p = (ty0 + pyl) * 64 + tx0 + pxl;

  // ---- prefetch Q (overlaps DMA issue) ----
  const unsigned short* qp = Q + (base + p) * 64 + sub * 16;
  const uint4 qa = *(const uint4*)qp;
  const uint4 qb = *(const uint4*)(qp + 8);

  // ---- issue K-halo DMA, then V-halo DMA (1152 16B chunks each) ----
#pragma unroll
  for (int it = 0; it < 5; ++it) {
    const int i = it * 256 + tid;
    if (i < 1152) {  // wave-uniform (wave chunk spans stay inside/outside)
      const int r = i >> 3;
      const int cg = (tid & 7) ^ (r & 7);  // pre-swizzled global chunk
      const int gy = ty0 - 2 + r / 12;
      const int gx = tx0 - 2 + r % 12;
      const unsigned short* src =
          ((unsigned)gy < 64u && (unsigned)gx < 64u)
              ? K + (base + (size_t)(gy * 64 + gx)) * 64 + cg * 8
              : Zp + cg * 8;
      g2l16(src, &H[(it * 32 + wv * 8) * 64]);
    }
  }
#pragma unroll
  for (int it = 0; it < 5; ++it) {
    const int i = it * 256 + tid;
    if (i < 1152) {
      const int r = i >> 3;
      const int cg = (tid & 7) ^ (r & 7);
      const int gy = ty0 - 2 + r / 12;
      const int gx = tx0 - 2 + r % 12;
      const unsigned short* src =
          ((unsigned)gy < 64u && (unsigned)gx < 64u)
              ? V + (base + (size_t)(gy * 64 + gx)) * 64 + cg * 8
              : Zp + cg * 8;
      g2l16(src, &H[9216 + (it * 32 + wv * 8) * 64]);
    }
  }

  // ---- wait K only (V stays in flight), all waves ----
  asm volatile("s_waitcnt vmcnt(4)" ::: "memory");
  __builtin_amdgcn_s_barrier();
  __builtin_amdgcn_sched_barrier(0);

  // ---- QK dots over own 16 dims, packed bf16 via v_dot2_f32_bf16 ----
  float dots[25];
#pragma unroll
  for (int fy = 0; fy < 5; ++fy) {
#pragma unroll
    for (int fx = 0; fx < 5; ++fx) {
      const int row = (pyl + fy) * 12 + pxl + fx;
      const int swz = (row & 7) << 3;  // shorts
      const unsigned short* hr = &H[row * 64];
      const uint4 ka = *(const uint4*)(hr + ((sub * 16) ^ swz));
      const uint4 kb = *(const uint4*)(hr + ((sub * 16 + 8) ^ swz));
      float d = 0.f;
      d = dot2bf(d, qa.x, ka.x);
      d = dot2bf(d, qa.y, ka.y);
      d = dot2bf(d, qa.z, ka.z);
      d = dot2bf(d, qa.w, ka.w);
      d = dot2bf(d, qb.x, kb.x);
      d = dot2bf(d, qb.y, kb.y);
      d = dot2bf(d, qb.z, kb.z);
      d = dot2bf(d, qb.w, kb.w);
      dots[fy * 5 + fx] = d;
    }
  }

  // ---- quad combine: lanes 4t..4t+3 are intra-wave ----
#pragma unroll
  for (int f = 0; f < 25; ++f) {
    dots[f] += __shfl_xor(dots[f], 1, 64);
    dots[f] += __shfl_xor(dots[f], 2, 64);
  }

  // ---- softmax (registers only; still overlapping V DMA) ----
  float mx = -1e30f;
#pragma unroll
  for (int f = 0; f < 25; ++f) {
    dots[f] *= kScale;
    mx = fmaxf(mx, dots[f]);
  }
  float sum = 0.f;
#pragma unroll
  for (int f = 0; f < 25; ++f) {
    dots[f] = __expf(dots[f] - mx);
    sum += dots[f];
  }
  const float inv = 1.f / sum;
#pragma unroll
  for (int f = 0; f < 25; ++f) dots[f] *= inv;

  // ---- V ready? drain DMA + barrier ----
  asm volatile("s_waitcnt vmcnt(0)" ::: "memory");
  __builtin_amdgcn_s_barrier();
  __builtin_amdgcn_sched_barrier(0);

  const int b = bh >> 3, h = bh & 7;
  unsigned short* op = AO + ((size_t)(b * kN + p)) * 512 + h * 64 + sub * 16;
#pragma unroll 1
  for (int hh = 0; hh < 2; ++hh) {  // two 8-dim passes (register pressure)
    float o[8];
#pragma unroll
    for (int j = 0; j < 8; ++j) o[j] = 0.f;
#pragma unroll
    for (int fy = 0; fy < 5; ++fy) {
#pragma unroll
      for (int fx = 0; fx < 5; ++fx) {
        const int row = (pyl + fy) * 12 + pxl + fx;
        const int swz = (row & 7) << 3;  // shorts
        const uint4 va =
            *(const uint4*)&H[9216 + row * 64 + ((sub * 16 + hh * 8) ^ swz)];
        const float wf = dots[fy * 5 + fx];
        o[0] = fmaf(wf, blo(va.x), o[0]);
        o[1] = fmaf(wf, bhi(va.x), o[1]);
        o[2] = fmaf(wf, blo(va.y), o[2]);
        o[3] = fmaf(wf, bhi(va.y), o[3]);
        o[4] = fmaf(wf, blo(va.z), o[4]);
        o[5] = fmaf(wf, bhi(va.z), o[5]);
        o[6] = fmaf(wf, blo(va.w), o[6]);
        o[7] = fmaf(wf, bhi(va.w), o[7]);
      }
    }
    u16x8 pk;
#pragma unroll
    for (int j = 0; j < 8; ++j) pk[j] = f2b(o[j]);
    *(u16x8*)(op + hh * 8) = pk;
  }
}

}  // namespace

extern "C" void kernel_launch(void* const* d_in, const int* in_sizes, int n_in,
                              void* d_out, int out_size, void* d_ws,
                              size_t ws_size, hipStream_t stream) {
  (void)in_sizes; (void)n_in; (void)out_size; (void)ws_size;
  const float* x = (const float*)d_in[0];      // [4,4096,512]
  const float* w_qkv = (const float*)d_in[1];  // [1536,512]
  const float* w_out = (const float*)d_in[2];  // [512,512]
  const float* b_out = (const float*)d_in[3];  // [512]
  float* out = (float*)d_out;                  // [4,4096,512] fp32

  unsigned short* ws0 = (unsigned short*)d_ws;
  unsigned short* wqkvb = ws0;              //   786,432
  unsigned short* woutb = ws0 + 786432;     //   262,144
  unsigned short* xb = ws0 + 1048576;       // 8,388,608
  unsigned short* Qb = ws0 + 9437184;       // 8,388,608
  unsigned short* Kb = ws0 + 17825792;      // 8,388,608
  unsigned short* Vb = ws0 + 26214400;      // 8,388,608
  unsigned short* AO = ws0 + 34603008;      // 8,388,608
  unsigned short* Zp = ws0 + 42991616;      // 64 shorts zero pad -> 86 MB

  cvt_all<<<4608, 256, 0, stream>>>(w_qkv, w_out, x, wqkvb, woutb, xb, Zp);
  gemm_qkv<<<1536, 256, 0, stream>>>(xb, wqkvb, Qb, Kb, Vb);
  attn_q4<<<2048, 256, 0, stream>>>(Qb, Kb, Vb, Zp, AO);
  gemm_out<<<512, 256, 0, stream>>>(AO, woutb, b_out, out);
}

// Round 10
// 179.720 us; speedup vs baseline: 1.0656x; 1.0656x over previous
//
#include <hip/hip_runtime.h>
#include <cstddef>
#include <cstdint>

// LocalAttention MI355X round 18.
//   cvt_all:   fp32 -> bf16 + 128B zero pad (unchanged from r16).
//   gemm_qkv/gemm_out: dbuf REVERTED (r9: 64KB LDS cut residency 5->2
//              blocks/CU, 53.5us). Back to 1-phase, but tile raised to
//              256x128 (512 thr, 8 waves = 4M x 2N, per-wave code identical:
//              acc[4][4], same frag reads, same XOR staging swizzle).
//              Intensity 64->85 FLOP/staged-byte, blocks 1536->768, LDS
//              48KB -> 3 blocks/CU = 24 waves. (512,3) = same 85-VGPR cap
//              regime as the proven (256,3) (cap=256/arg2, r11-r13;
//              acc lives in AGPRs — rocprof's 132 at cap-85 in r9 shows
//              VGPR_Count reports arch+AGPR).
//   attn_q4:   async-DMA fill (unchanged from r16; <41us, out of top-5).
// ws: 86 MB + 128 B of 256 MiB.

namespace {

typedef short s16x8 __attribute__((ext_vector_type(8)));
typedef unsigned short u16x8 __attribute__((ext_vector_type(8)));
typedef float f32x4 __attribute__((ext_vector_type(4)));

constexpr int kHeads = 8;
constexpr int kN = 4096;          // pixels per image
constexpr float kScale = 0.125f;  // 64^-0.5

__device__ inline float blo(unsigned u) {
  return __uint_as_float(u << 16);
}
__device__ inline float bhi(unsigned u) {
  return __uint_as_float(u & 0xffff0000u);
}
__device__ inline unsigned short f2b(float x) {
  unsigned u = __float_as_uint(x);  // RNE
  return (unsigned short)((u + 0x7fffu + ((u >> 16) & 1u)) >> 16);
}

// d += dot2(packed bf16 a, packed bf16 b), f32 accumulate (CDNA4 VOP3P)
__device__ __forceinline__ float dot2bf(float d, unsigned a, unsigned b) {
  asm("v_dot2_f32_bf16 %0, %1, %2, %0" : "+v"(d) : "v"(a), "v"(b));
  return d;
}

// async global->LDS, 16 B per lane; LDS dest = wave-uniform base + lane*16
__device__ __forceinline__ void g2l16(const unsigned short* g,
                                      unsigned short* l) {
  __builtin_amdgcn_global_load_lds(
      (const __attribute__((address_space(1))) void*)g,
      (__attribute__((address_space(3))) void*)l, 16, 0, 0);
}

// ---------------- fp32 -> bf16 for all three tensors -------------------------
__global__ __launch_bounds__(256) void cvt_all(
    const float* __restrict__ wq, const float* __restrict__ wo,
    const float* __restrict__ x, unsigned short* __restrict__ wqb,
    unsigned short* __restrict__ wob, unsigned short* __restrict__ xb,
    unsigned short* __restrict__ zp) {
  const int i = blockIdx.x * 256 + threadIdx.x;  // 0..1179647
  if (i < 16) ((unsigned long long*)zp)[i] = 0ull;  // 128B zero pad for attn
  const float* src;
  unsigned short* dst;
  int off;
  if (i < 98304) {
    src = wq; dst = wqb; off = i;
  } else if (i < 131072) {
    src = wo; dst = wob; off = i - 98304;
  } else {
    src = x; dst = xb; off = i - 131072;
  }
  const float4 a = ((const float4*)src)[off * 2];
  const float4 b = ((const float4*)src)[off * 2 + 1];
  u16x8 o;
  o[0] = f2b(a.x); o[1] = f2b(a.y); o[2] = f2b(a.z); o[3] = f2b(a.w);
  o[4] = f2b(b.x); o[5] = f2b(b.y); o[6] = f2b(b.z); o[7] = f2b(b.w);
  *(u16x8*)(dst + (size_t)off * 8) = o;
}

// ---------------- MFMA GEMM core: 256x128 tile, K=512, BK=64, 1-phase -------
// 512 threads = 8 waves (wm = wv>>1 in 0..3, wn = wv&1). XOR-swizzled
// staging: lane stages logical k-seg (lane&7)^rsub so the g2l16-forced
// layout (base + lane*16B) yields bank-spread ds_read_b128.
__device__ __forceinline__ void mfma_512(const unsigned short* __restrict__ A,
                                         const unsigned short* __restrict__ W,
                                         int m0, int n0, int tid,
                                         unsigned short* As, unsigned short* Bs,
                                         f32x4 (&acc)[4][4]) {
  const int lane = tid & 63;
  const int wv = tid >> 6;             // 0..7
  const int wm = wv >> 1, wn = wv & 1;
  const int rsub = lane >> 3;          // row within 8-row group
  const int slog = (lane & 7) ^ rsub;  // logical k-seg this lane stages
#pragma unroll
  for (int i = 0; i < 4; ++i)
#pragma unroll
    for (int j = 0; j < 4; ++j) acc[i][j] = f32x4{0.f, 0.f, 0.f, 0.f};

  for (int k0 = 0; k0 < 512; k0 += 64) {
#pragma unroll
    for (int it = 0; it < 4; ++it) {  // A: 256 rows
      const int row = it * 64 + wv * 8 + rsub;
      g2l16(A + (size_t)(m0 + row) * 512 + k0 + slog * 8,
            As + (it * 64 + wv * 8) * 64);
    }
#pragma unroll
    for (int it = 0; it < 2; ++it) {  // B: 128 rows
      const int row = it * 64 + wv * 8 + rsub;
      g2l16(W + (size_t)(n0 + row) * 512 + k0 + slog * 8,
            Bs + (it * 64 + wv * 8) * 64);
    }
    __syncthreads();
#pragma unroll
    for (int kh = 0; kh < 2; ++kh) {
      s16x8 af[4], bf[4];
      const int q = kh * 4 + (lane >> 4);  // logical k-seg wanted
#pragma unroll
      for (int i = 0; i < 4; ++i) {
        const int Ra = wm * 64 + i * 16 + (lane & 15);
        af[i] = *(const s16x8*)&As[Ra * 64 + ((q ^ (Ra & 7)) * 8)];
        const int Rb = wn * 64 + i * 16 + (lane & 15);
        bf[i] = *(const s16x8*)&Bs[Rb * 64 + ((q ^ (Rb & 7)) * 8)];
      }
#pragma unroll
      for (int i = 0; i < 4; ++i)
#pragma unroll
        for (int j = 0; j < 4; ++j)
          acc[i][j] = __builtin_amdgcn_mfma_f32_16x16x32_bf16(
              af[i], bf[j], acc[i][j], 0, 0, 0);
    }
    __syncthreads();
  }
}

// ---------------- QKV projection GEMM, full M=16384 --------------------------
__global__ __launch_bounds__(512, 3) void gemm_qkv(
    const unsigned short* __restrict__ A, const unsigned short* __restrict__ W,
    unsigned short* __restrict__ Qb, unsigned short* __restrict__ Kb,
    unsigned short* __restrict__ Vb) {
  __shared__ unsigned short As[16384], Bs[8192];  // 32 KB + 16 KB
  const int tid = threadIdx.x;
  const int id = blockIdx.x;          // 0..767
  const int xcd = id & 7;
  const int j = id >> 3;              // 0..95
  const int by = xcd * 8 + j / 12;    // 0..63
  const int bx = j % 12;
  f32x4 acc[4][4];
  mfma_512(A, W, by * 256, bx * 128, tid, As, Bs, acc);

  const int lane = tid & 63;
  const int wv = tid >> 6;
  const int wm = wv >> 1, wn = wv & 1;
  const int cn = bx * 128 + wn * 64;  // 64-aligned => head/qkv wave-uniform
  unsigned short* dst = (cn < 512) ? Qb : (cn < 1024 ? Kb : Vb);
  const int head = (cn >> 6) & 7;
  const int colb = lane & 15;
#pragma unroll
  for (int mi = 0; mi < 4; ++mi) {
#pragma unroll
    for (int r = 0; r < 4; ++r) {
      const int m = by * 256 + wm * 64 + mi * 16 + (lane >> 4) * 4 + r;
      const int b = m >> 12;
      const int p = m & 4095;
      unsigned short* o =
          dst + ((size_t)(b * kHeads + head) * kN + p) * 64 + colb;
#pragma unroll
      for (int ni = 0; ni < 4; ++ni) o[ni * 16] = f2b(acc[mi][ni][r]);
    }
  }
}

// ---------------- out-projection GEMM ----------------------------------------
__global__ __launch_bounds__(512, 3) void gemm_out(
    const unsigned short* __restrict__ A, const unsigned short* __restrict__ W,
    const float* __restrict__ bias, float* __restrict__ out) {
  __shared__ unsigned short As[16384], Bs[8192];
  const int tid = threadIdx.x;
  const int id = blockIdx.x;           // 0..255
  const int xcd = id & 7;
  const int j = id >> 3;               // 0..31
  const int by = xcd * 8 + (j >> 2);   // 0..63
  const int bx = j & 3;
  f32x4 acc[4][4];
  mfma_512(A, W, by * 256, bx * 128, tid, As, Bs, acc);

  const int lane = tid & 63;
  const int wv = tid >> 6;
  const int wm = wv >> 1, wn = wv & 1;
  float bvr[4];
#pragma unroll
  for (int ni = 0; ni < 4; ++ni)
    bvr[ni] = bias[bx * 128 + wn * 64 + ni * 16 + (lane & 15)];
#pragma unroll
  for (int mi = 0; mi < 4; ++mi) {
#pragma unroll
    for (int r = 0; r < 4; ++r) {
      const int m = by * 256 + wm * 64 + mi * 16 + (lane >> 4) * 4 + r;
      float* o = out + (size_t)m * 512 + bx * 128 + wn * 64 + (lane & 15);
#pragma unroll
      for (int ni = 0; ni < 4; ++ni) o[ni * 16] = acc[mi][ni][r] + bvr[ni];
    }
  }
}

// ---------------- fused local attention, async-DMA fill ----------------------
// 256 threads/block, 8x8 pixel tile, quad-split (4 threads/pixel x 16 dims).
// H0 = K halo, H1 = V halo, 144 rows x 64 shorts each (36.86 KB total).
// Both fills are global_load_lds salvos issued at kernel start. Swizzle on
// the GLOBAL source (lane fetches chunk (lane&7)^(row&7)), LDS linear.
// OOB rows pull from a zeroed 128B ws slab. vmcnt(4): K drained, V in
// flight; QK + softmax overlap the V DMA; vmcnt(0)+barrier before PV.
__global__ __launch_bounds__(256) void attn_q4(
    const unsigned short* __restrict__ Q, const unsigned short* __restrict__ K,
    const unsigned short* __restrict__ V, const unsigned short* __restrict__ Zp,
    unsigned short* __restrict__ AO) {
  __shared__ unsigned short H[2 * 144 * 64];  // 36.86 KB: [0]=K, [9216]=V
  const int tid = threadIdx.x;  // 0..255
  const int id = blockIdx.x;    // 0..2047
  const int wv = tid >> 6;
  // XCD-clustered mapping: 4 heads' K/V (2 MB) per XCD L2.
  const int xcd = id & 7;
  const int k8 = id >> 3;              // 0..255
  const int bh = xcd * 4 + (k8 >> 6);  // 0..31
  const int tile = k8 & 63;            // 0..63
  const int ty0 = (tile >> 3) * 8, tx0 = (tile & 7) * 8;
  const size_t base = (size_t)bh * kN;
  const int pix = tid >> 2;  // 0..63
  const int sub = tid & 3;   // which 16-dim quarter
  const int pyl = pix >> 3, pxl = pix & 7;
  const int p = (ty0 + pyl) * 64 + tx0 + pxl;

  // ---- prefetch Q (overlaps DMA issue) ----
  const unsigned short* qp = Q + (base + p) * 64 + sub * 16;
  const uint4 qa = *(const uint4*)qp;
  const uint4 qb = *(const uint4*)(qp + 8);

  // ---- issue K-halo DMA, then V-halo DMA (1152 16B chunks each) ----
#pragma unroll
  for (int it = 0; it < 5; ++it) {
    const int i = it * 256 + tid;
    if (i < 1152) {  // wave-uniform (wave chunk spans stay inside/outside)
      const int r = i >> 3;
      const int cg = (tid & 7) ^ (r & 7);  // pre-swizzled global chunk
      const int gy = ty0 - 2 + r / 12;
      const int gx = tx0 - 2 + r % 12;
      const unsigned short* src =
          ((unsigned)gy < 64u && (unsigned)gx < 64u)
              ? K + (base + (size_t)(gy * 64 + gx)) * 64 + cg * 8
              : Zp + cg * 8;
      g2l16(src, &H[(it * 32 + wv * 8) * 64]);
    }
  }
#pragma unroll
  for (int it = 0; it < 5; ++it) {
    const int i = it * 256 + tid;
    if (i < 1152) {
      const int r = i >> 3;
      const int cg = (tid & 7) ^ (r & 7);
      const int gy = ty0 - 2 + r / 12;
      const int gx = tx0 - 2 + r % 12;
      const unsigned short* src =
          ((unsigned)gy < 64u && (unsigned)gx < 64u)
              ? V + (base + (size_t)(gy * 64 + gx)) * 64 + cg * 8
              : Zp + cg * 8;
      g2l16(src, &H[9216 + (it * 32 + wv * 8) * 64]);
    }
  }

  // ---- wait K only (V stays in flight), all waves ----
  asm volatile("s_waitcnt vmcnt(4)" ::: "memory");
  __builtin_amdgcn_s_barrier();
  __builtin_amdgcn_sched_barrier(0);

  // ---- QK dots over own 16 dims, packed bf16 via v_dot2_f32_bf16 ----
  float dots[25];
#pragma unroll
  for (int fy = 0; fy < 5; ++fy) {
#pragma unroll
    for (int fx = 0; fx < 5; ++fx) {
      const int row = (pyl + fy) * 12 + pxl + fx;
      const int swz = (row & 7) << 3;  // shorts
      const unsigned short* hr = &H[row * 64];
      const uint4 ka = *(const uint4*)(hr + ((sub * 16) ^ swz));
      const uint4 kb = *(const uint4*)(hr + ((sub * 16 + 8) ^ swz));
      float d = 0.f;
      d = dot2bf(d, qa.x, ka.x);
      d = dot2bf(d, qa.y, ka.y);
      d = dot2bf(d, qa.z, ka.z);
      d = dot2bf(d, qa.w, ka.w);
      d = dot2bf(d, qb.x, kb.x);
      d = dot2bf(d, qb.y, kb.y);
      d = dot2bf(d, qb.z, kb.z);
      d = dot2bf(d, qb.w, kb.w);
      dots[fy * 5 + fx] = d;
    }
  }

  // ---- quad combine: lanes 4t..4t+3 are intra-wave ----
#pragma unroll
  for (int f = 0; f < 25; ++f) {
    dots[f] += __shfl_xor(dots[f], 1, 64);
    dots[f] += __shfl_xor(dots[f], 2, 64);
  }

  // ---- softmax (registers only; still overlapping V DMA) ----
  float mx = -1e30f;
#pragma unroll
  for (int f = 0; f < 25; ++f) {
    dots[f] *= kScale;
    mx = fmaxf(mx, dots[f]);
  }
  float sum = 0.f;
#pragma unroll
  for (int f = 0; f < 25; ++f) {
    dots[f] = __expf(dots[f] - mx);
    sum += dots[f];
  }
  const float inv = 1.f / sum;
#pragma unroll
  for (int f = 0; f < 25; ++f) dots[f] *= inv;

  // ---- V ready? drain DMA + barrier ----
  asm volatile("s_waitcnt vmcnt(0)" ::: "memory");
  __builtin_amdgcn_s_barrier();
  __builtin_amdgcn_sched_barrier(0);

  const int b = bh >> 3, h = bh & 7;
  unsigned short* op = AO + ((size_t)(b * kN + p)) * 512 + h * 64 + sub * 16;
#pragma unroll 1
  for (int hh = 0; hh < 2; ++hh) {  // two 8-dim passes (register pressure)
    float o[8];
#pragma unroll
    for (int j = 0; j < 8; ++j) o[j] = 0.f;
#pragma unroll
    for (int fy = 0; fy < 5; ++fy) {
#pragma unroll
      for (int fx = 0; fx < 5; ++fx) {
        const int row = (pyl + fy) * 12 + pxl + fx;
        const int swz = (row & 7) << 3;  // shorts
        const uint4 va =
            *(const uint4*)&H[9216 + row * 64 + ((sub * 16 + hh * 8) ^ swz)];
        const float wf = dots[fy * 5 + fx];
        o[0] = fmaf(wf, blo(va.x), o[0]);
        o[1] = fmaf(wf, bhi(va.x), o[1]);
        o[2] = fmaf(wf, blo(va.y), o[2]);
        o[3] = fmaf(wf, bhi(va.y), o[3]);
        o[4] = fmaf(wf, blo(va.z), o[4]);
        o[5] = fmaf(wf, bhi(va.z), o[5]);
        o[6] = fmaf(wf, blo(va.w), o[6]);
        o[7] = fmaf(wf, bhi(va.w), o[7]);
      }
    }
    u16x8 pk;
#pragma unroll
    for (int j = 0; j < 8; ++j) pk[j] = f2b(o[j]);
    *(u16x8*)(op + hh * 8) = pk;
  }
}

}  // namespace

extern "C" void kernel_launch(void* const* d_in, const int* in_sizes, int n_in,
                              void* d_out, int out_size, void* d_ws,
                              size_t ws_size, hipStream_t stream) {
  (void)in_sizes; (void)n_in; (void)out_size; (void)ws_size;
  const float* x = (const float*)d_in[0];      // [4,4096,512]
  const float* w_qkv = (const float*)d_in[1];  // [1536,512]
  const float* w_out = (const float*)d_in[2];  // [512,512]
  const float* b_out = (const float*)d_in[3];  // [512]
  float* out = (float*)d_out;                  // [4,4096,512] fp32

  unsigned short* ws0 = (unsigned short*)d_ws;
  unsigned short* wqkvb = ws0;              //   786,432
  unsigned short* woutb = ws0 + 786432;     //   262,144
  unsigned short* xb = ws0 + 1048576;       // 8,388,608
  unsigned short* Qb = ws0 + 9437184;       // 8,388,608
  unsigned short* Kb = ws0 + 17825792;      // 8,388,608
  unsigned short* Vb = ws0 + 26214400;      // 8,388,608
  unsigned short* AO = ws0 + 34603008;      // 8,388,608
  unsigned short* Zp = ws0 + 42991616;      // 64 shorts zero pad -> 86 MB

  cvt_all<<<4608, 256, 0, stream>>>(w_qkv, w_out, x, wqkvb, woutb, xb, Zp);
  gemm_qkv<<<768, 512, 0, stream>>>(xb, wqkvb, Qb, Kb, Vb);
  attn_q4<<<2048, 256, 0, stream>>>(Qb, Kb, Vb, Zp, AO);
  gemm_out<<<256, 512, 0, stream>>>(AO, woutb, b_out, out);
}

// Round 11
// 173.543 us; speedup vs baseline: 1.1035x; 1.0356x over previous
//
#include <hip/hip_runtime.h>
#include <cstddef>
#include <cstdint>

// LocalAttention MI355X round 19.
//   Base = r16 anchor (165.3 us): 128^2 1-phase GEMMs (256,3), async-DMA attn.
//   Single change: gemm_qkv core -> counted-vmcnt double-buffer (T4).
//     r17's dbuf failed because __syncthreads drains vmcnt(0): stage(k+1)
//     was issued early but then fully drained at the barrier => latency
//     never hidden + 64KB LDS cost residency. Now: raw s_barrier only,
//     s_waitcnt vmcnt(8) before barrier-1 (stage(k) drained, stage(k+1)'s
//     8 loads stay in flight across the whole compute phase).
//   gemm_out: r16 1-phase core (control).
//   attn_q4, cvt_all: unchanged from r16.
// ws: 86 MB + 128 B of 256 MiB.

namespace {

typedef short s16x8 __attribute__((ext_vector_type(8)));
typedef unsigned short u16x8 __attribute__((ext_vector_type(8)));
typedef float f32x4 __attribute__((ext_vector_type(4)));

constexpr int kHeads = 8;
constexpr int kN = 4096;          // pixels per image
constexpr float kScale = 0.125f;  // 64^-0.5

__device__ inline float blo(unsigned u) {
  return __uint_as_float(u << 16);
}
__device__ inline float bhi(unsigned u) {
  return __uint_as_float(u & 0xffff0000u);
}
__device__ inline unsigned short f2b(float x) {
  unsigned u = __float_as_uint(x);  // RNE
  return (unsigned short)((u + 0x7fffu + ((u >> 16) & 1u)) >> 16);
}

// d += dot2(packed bf16 a, packed bf16 b), f32 accumulate (CDNA4 VOP3P)
__device__ __forceinline__ float dot2bf(float d, unsigned a, unsigned b) {
  asm("v_dot2_f32_bf16 %0, %1, %2, %0" : "+v"(d) : "v"(a), "v"(b));
  return d;
}

// async global->LDS, 16 B per lane; LDS dest = wave-uniform base + lane*16
__device__ __forceinline__ void g2l16(const unsigned short* g,
                                      unsigned short* l) {
  __builtin_amdgcn_global_load_lds(
      (const __attribute__((address_space(1))) void*)g,
      (__attribute__((address_space(3))) void*)l, 16, 0, 0);
}

// ---------------- fp32 -> bf16 for all three tensors -------------------------
__global__ __launch_bounds__(256) void cvt_all(
    const float* __restrict__ wq, const float* __restrict__ wo,
    const float* __restrict__ x, unsigned short* __restrict__ wqb,
    unsigned short* __restrict__ wob, unsigned short* __restrict__ xb,
    unsigned short* __restrict__ zp) {
  const int i = blockIdx.x * 256 + threadIdx.x;  // 0..1179647
  if (i < 16) ((unsigned long long*)zp)[i] = 0ull;  // 128B zero pad for attn
  const float* src;
  unsigned short* dst;
  int off;
  if (i < 98304) {
    src = wq; dst = wqb; off = i;
  } else if (i < 131072) {
    src = wo; dst = wob; off = i - 98304;
  } else {
    src = x; dst = xb; off = i - 131072;
  }
  const float4 a = ((const float4*)src)[off * 2];
  const float4 b = ((const float4*)src)[off * 2 + 1];
  u16x8 o;
  o[0] = f2b(a.x); o[1] = f2b(a.y); o[2] = f2b(a.z); o[3] = f2b(a.w);
  o[4] = f2b(b.x); o[5] = f2b(b.y); o[6] = f2b(b.z); o[7] = f2b(b.w);
  *(u16x8*)(dst + (size_t)off * 8) = o;
}

// ---------------- staging helper: one 128x64 half-K tile pair ---------------
__device__ __forceinline__ void stage64(const unsigned short* __restrict__ A,
                                        const unsigned short* __restrict__ W,
                                        int m0, int n0, int k0, int wv,
                                        int rsub, int slog,
                                        unsigned short* As,
                                        unsigned short* Bs) {
#pragma unroll
  for (int it = 0; it < 4; ++it) {
    const int g = wv * 4 + it;  // 0..15 -> 8-row group
    const int row = g * 8 + rsub;
    g2l16(A + (size_t)(m0 + row) * 512 + k0 + slog * 8, As + g * 512);
    g2l16(W + (size_t)(n0 + row) * 512 + k0 + slog * 8, Bs + g * 512);
  }
}

// ---------------- compute helper: 32 MFMA on one staged BK=64 tile ----------
__device__ __forceinline__ void compute64(const unsigned short* __restrict__ as,
                                          const unsigned short* __restrict__ bs,
                                          int lane, int wm, int wn,
                                          f32x4 (&acc)[4][4]) {
#pragma unroll
  for (int kh = 0; kh < 2; ++kh) {
    s16x8 af[4], bf[4];
    const int q = kh * 4 + (lane >> 4);  // logical k-seg wanted
#pragma unroll
    for (int i = 0; i < 4; ++i) {
      const int Ra = wm * 64 + i * 16 + (lane & 15);
      af[i] = *(const s16x8*)&as[Ra * 64 + ((q ^ (Ra & 7)) * 8)];
      const int Rb = wn * 64 + i * 16 + (lane & 15);
      bf[i] = *(const s16x8*)&bs[Rb * 64 + ((q ^ (Rb & 7)) * 8)];
    }
#pragma unroll
    for (int i = 0; i < 4; ++i)
#pragma unroll
      for (int j = 0; j < 4; ++j)
        acc[i][j] = __builtin_amdgcn_mfma_f32_16x16x32_bf16(
            af[i], bf[j], acc[i][j], 0, 0, 0);
  }
}

// ---------------- 1-phase core (gemm_out control) ----------------------------
__device__ __forceinline__ void mfma_512(const unsigned short* __restrict__ A,
                                         const unsigned short* __restrict__ W,
                                         int m0, int n0, int tid,
                                         unsigned short* As, unsigned short* Bs,
                                         f32x4 (&acc)[4][4]) {
  const int lane = tid & 63;
  const int wv = tid >> 6;
  const int wm = wv & 1, wn = wv >> 1;
  const int rsub = lane >> 3;
  const int slog = (lane & 7) ^ rsub;
#pragma unroll
  for (int i = 0; i < 4; ++i)
#pragma unroll
    for (int j = 0; j < 4; ++j) acc[i][j] = f32x4{0.f, 0.f, 0.f, 0.f};

  for (int k0 = 0; k0 < 512; k0 += 64) {
    stage64(A, W, m0, n0, k0, wv, rsub, slog, As, Bs);
    __syncthreads();
    compute64(As, Bs, lane, wm, wn, acc);
    __syncthreads();
  }
}

// ---------------- counted-vmcnt double-buffered core (gemm_qkv) -------------
// Per iter: issue stage(k+1)->buf^1, vmcnt(8) [stage(k) drained, stage(k+1)
// in flight], s_barrier, compute(k), s_barrier. No vmcnt(0) in the loop.
__device__ __forceinline__ void mfma_512_db(
    const unsigned short* __restrict__ A, const unsigned short* __restrict__ W,
    int m0, int n0, int tid, unsigned short* As, unsigned short* Bs,
    f32x4 (&acc)[4][4]) {
  const int lane = tid & 63;
  const int wv = tid >> 6;
  const int wm = wv & 1, wn = wv >> 1;
  const int rsub = lane >> 3;
  const int slog = (lane & 7) ^ rsub;
#pragma unroll
  for (int i = 0; i < 4; ++i)
#pragma unroll
    for (int j = 0; j < 4; ++j) acc[i][j] = f32x4{0.f, 0.f, 0.f, 0.f};

  stage64(A, W, m0, n0, 0, wv, rsub, slog, As, Bs);
  int buf = 0;
#pragma unroll 1
  for (int k = 0; k < 8; ++k) {
    if (k < 7)
      stage64(A, W, m0, n0, (k + 1) * 64, wv, rsub, slog,
              As + (buf ^ 1) * 8192, Bs + (buf ^ 1) * 8192);
    if (k < 7)
      asm volatile("s_waitcnt vmcnt(8)" ::: "memory");
    else
      asm volatile("s_waitcnt vmcnt(0)" ::: "memory");
    asm volatile("s_barrier" ::: "memory");
    __builtin_amdgcn_sched_barrier(0);
    compute64(As + buf * 8192, Bs + buf * 8192, lane, wm, wn, acc);
    asm volatile("s_barrier" ::: "memory");
    buf ^= 1;
  }
}

// ---------------- QKV projection GEMM, full M=16384 --------------------------
__global__ __launch_bounds__(256, 3) void gemm_qkv(
    const unsigned short* __restrict__ A, const unsigned short* __restrict__ W,
    unsigned short* __restrict__ Qb, unsigned short* __restrict__ Kb,
    unsigned short* __restrict__ Vb) {
  __shared__ unsigned short As[16384], Bs[16384];  // 32 KB each (dbuf)
  const int tid = threadIdx.x;
  const int id = blockIdx.x;
  const int xcd = id & 7;
  const int j = id >> 3;            // 0..191
  const int by = xcd * 16 + j / 12; // 0..127
  const int bx = j % 12;
  f32x4 acc[4][4];
  mfma_512_db(A, W, by * 128, bx * 128, tid, As, Bs, acc);

  const int lane = tid & 63;
  const int wv = tid >> 6;
  const int wm = wv & 1, wn = wv >> 1;
  const int cn = bx * 128 + wn * 64;  // 64-aligned => head/qkv wave-uniform
  unsigned short* dst = (cn < 512) ? Qb : (cn < 1024 ? Kb : Vb);
  const int head = (cn >> 6) & 7;
  const int colb = lane & 15;
#pragma unroll
  for (int mi = 0; mi < 4; ++mi) {
#pragma unroll
    for (int r = 0; r < 4; ++r) {
      const int m = by * 128 + wm * 64 + mi * 16 + (lane >> 4) * 4 + r;
      const int b = m >> 12;
      const int p = m & 4095;
      unsigned short* o =
          dst + ((size_t)(b * kHeads + head) * kN + p) * 64 + colb;
#pragma unroll
      for (int ni = 0; ni < 4; ++ni) o[ni * 16] = f2b(acc[mi][ni][r]);
    }
  }
}

// ---------------- out-projection GEMM ----------------------------------------
__global__ __launch_bounds__(256, 3) void gemm_out(
    const unsigned short* __restrict__ A, const unsigned short* __restrict__ W,
    const float* __restrict__ bias, float* __restrict__ out) {
  __shared__ unsigned short As[8192], Bs[8192];
  const int tid = threadIdx.x;
  const int id = blockIdx.x;
  const int xcd = id & 7;
  const int j = id >> 3;               // 0..63
  const int by = xcd * 16 + (j >> 2);  // 0..127
  const int bx = j & 3;
  f32x4 acc[4][4];
  mfma_512(A, W, by * 128, bx * 128, tid, As, Bs, acc);

  const int lane = tid & 63;
  const int wv = tid >> 6;
  const int wm = wv & 1, wn = wv >> 1;
  float bvr[4];
#pragma unroll
  for (int ni = 0; ni < 4; ++ni)
    bvr[ni] = bias[bx * 128 + wn * 64 + ni * 16 + (lane & 15)];
#pragma unroll
  for (int mi = 0; mi < 4; ++mi) {
#pragma unroll
    for (int r = 0; r < 4; ++r) {
      const int m = by * 128 + wm * 64 + mi * 16 + (lane >> 4) * 4 + r;
      float* o = out + (size_t)m * 512 + bx * 128 + wn * 64 + (lane & 15);
#pragma unroll
      for (int ni = 0; ni < 4; ++ni) o[ni * 16] = acc[mi][ni][r] + bvr[ni];
    }
  }
}

// ---------------- fused local attention, async-DMA fill ----------------------
// 256 threads/block, 8x8 pixel tile, quad-split (4 threads/pixel x 16 dims).
// H0 = K halo, H1 = V halo, 144 rows x 64 shorts each (36.86 KB total).
// Both fills are global_load_lds salvos issued at kernel start. Swizzle on
// the GLOBAL source (lane fetches chunk (lane&7)^(row&7)), LDS linear.
// OOB rows pull from a zeroed 128B ws slab. vmcnt(4): K drained, V in
// flight; QK + softmax overlap the V DMA; vmcnt(0)+barrier before PV.
__global__ __launch_bounds__(256) void attn_q4(
    const unsigned short* __restrict__ Q, const unsigned short* __restrict__ K,
    const unsigned short* __restrict__ V, const unsigned short* __restrict__ Zp,
    unsigned short* __restrict__ AO) {
  __shared__ unsigned short H[2 * 144 * 64];  // 36.86 KB: [0]=K, [9216]=V
  const int tid = threadIdx.x;  // 0..255
  const int id = blockIdx.x;    // 0..2047
  const int wv = tid >> 6;
  // XCD-clustered mapping: 4 heads' K/V (2 MB) per XCD L2.
  const int xcd = id & 7;
  const int k8 = id >> 3;              // 0..255
  const int bh = xcd * 4 + (k8 >> 6);  // 0..31
  const int tile = k8 & 63;            // 0..63
  const int ty0 = (tile >> 3) * 8, tx0 = (tile & 7) * 8;
  const size_t base = (size_t)bh * kN;
  const int pix = tid >> 2;  // 0..63
  const int sub = tid & 3;   // which 16-dim quarter
  const int pyl = pix >> 3, pxl = pix & 7;
  const int p = (ty0 + pyl) * 64 + tx0 + pxl;

  // ---- prefetch Q (overlaps DMA issue) ----
  const unsigned short* qp = Q + (base + p) * 64 + sub * 16;
  const uint4 qa = *(const uint4*)qp;
  const uint4 qb = *(const uint4*)(qp + 8);

  // ---- issue K-halo DMA, then V-halo DMA (1152 16B chunks each) ----
#pragma unroll
  for (int it = 0; it < 5; ++it) {
    const int i = it * 256 + tid;
    if (i < 1152) {  // wave-uniform (wave chunk spans stay inside/outside)
      const int r = i >> 3;
      const int cg = (tid & 7) ^ (r & 7);  // pre-swizzled global chunk
      const int gy = ty0 - 2 + r / 12;
      const int gx = tx0 - 2 + r % 12;
      const unsigned short* src =
          ((unsigned)gy < 64u && (unsigned)gx < 64u)
              ? K + (base + (size_t)(gy * 64 + gx)) * 64 + cg * 8
              : Zp + cg * 8;
      g2l16(src, &H[(it * 32 + wv * 8) * 64]);
    }
  }
#pragma unroll
  for (int it = 0; it < 5; ++it) {
    const int i = it * 256 + tid;
    if (i < 1152) {
      const int r = i >> 3;
      const int cg = (tid & 7) ^ (r & 7);
      const int gy = ty0 - 2 + r / 12;
      const int gx = tx0 - 2 + r % 12;
      const unsigned short* src =
          ((unsigned)gy < 64u && (unsigned)gx < 64u)
              ? V + (base + (size_t)(gy * 64 + gx)) * 64 + cg * 8
              : Zp + cg * 8;
      g2l16(src, &H[9216 + (it * 32 + wv * 8) * 64]);
    }
  }

  // ---- wait K only (V stays in flight), all waves ----
  asm volatile("s_waitcnt vmcnt(4)" ::: "memory");
  __builtin_amdgcn_s_barrier();
  __builtin_amdgcn_sched_barrier(0);

  // ---- QK dots over own 16 dims, packed bf16 via v_dot2_f32_bf16 ----
  float dots[25];
#pragma unroll
  for (int fy = 0; fy < 5; ++fy) {
#pragma unroll
    for (int fx = 0; fx < 5; ++fx) {
      const int row = (pyl + fy) * 12 + pxl + fx;
      const int swz = (row & 7) << 3;  // shorts
      const unsigned short* hr = &H[row * 64];
      const uint4 ka = *(const uint4*)(hr + ((sub * 16) ^ swz));
      const uint4 kb = *(const uint4*)(hr + ((sub * 16 + 8) ^ swz));
      float d = 0.f;
      d = dot2bf(d, qa.x, ka.x);
      d = dot2bf(d, qa.y, ka.y);
      d = dot2bf(d, qa.z, ka.z);
      d = dot2bf(d, qa.w, ka.w);
      d = dot2bf(d, qb.x, kb.x);
      d = dot2bf(d, qb.y, kb.y);
      d = dot2bf(d, qb.z, kb.z);
      d = dot2bf(d, qb.w, kb.w);
      dots[fy * 5 + fx] = d;
    }
  }

  // ---- quad combine: lanes 4t..4t+3 are intra-wave ----
#pragma unroll
  for (int f = 0; f < 25; ++f) {
    dots[f] += __shfl_xor(dots[f], 1, 64);
    dots[f] += __shfl_xor(dots[f], 2, 64);
  }

  // ---- softmax (registers only; still overlapping V DMA) ----
  float mx = -1e30f;
#pragma unroll
  for (int f = 0; f < 25; ++f) {
    dots[f] *= kScale;
    mx = fmaxf(mx, dots[f]);
  }
  float sum = 0.f;
#pragma unroll
  for (int f = 0; f < 25; ++f) {
    dots[f] = __expf(dots[f] - mx);
    sum += dots[f];
  }
  const float inv = 1.f / sum;
#pragma unroll
  for (int f = 0; f < 25; ++f) dots[f] *= inv;

  // ---- V ready? drain DMA + barrier ----
  asm volatile("s_waitcnt vmcnt(0)" ::: "memory");
  __builtin_amdgcn_s_barrier();
  __builtin_amdgcn_sched_barrier(0);

  const int b = bh >> 3, h = bh & 7;
  unsigned short* op = AO + ((size_t)(b * kN + p)) * 512 + h * 64 + sub * 16;
#pragma unroll 1
  for (int hh = 0; hh < 2; ++hh) {  // two 8-dim passes (register pressure)
    float o[8];
#pragma unroll
    for (int j = 0; j < 8; ++j) o[j] = 0.f;
#pragma unroll
    for (int fy = 0; fy < 5; ++fy) {
#pragma unroll
      for (int fx = 0; fx < 5; ++fx) {
        const int row = (pyl + fy) * 12 + pxl + fx;
        const int swz = (row & 7) << 3;  // shorts
        const uint4 va =
            *(const uint4*)&H[9216 + row * 64 + ((sub * 16 + hh * 8) ^ swz)];
        const float wf = dots[fy * 5 + fx];
        o[0] = fmaf(wf, blo(va.x), o[0]);
        o[1] = fmaf(wf, bhi(va.x), o[1]);
        o[2] = fmaf(wf, blo(va.y), o[2]);
        o[3] = fmaf(wf, bhi(va.y), o[3]);
        o[4] = fmaf(wf, blo(va.z), o[4]);
        o[5] = fmaf(wf, bhi(va.z), o[5]);
        o[6] = fmaf(wf, blo(va.w), o[6]);
        o[7] = fmaf(wf, bhi(va.w), o[7]);
      }
    }
    u16x8 pk;
#pragma unroll
    for (int j = 0; j < 8; ++j) pk[j] = f2b(o[j]);
    *(u16x8*)(op + hh * 8) = pk;
  }
}

}  // namespace

extern "C" void kernel_launch(void* const* d_in, const int* in_sizes, int n_in,
                              void* d_out, int out_size, void* d_ws,
                              size_t ws_size, hipStream_t stream) {
  (void)in_sizes; (void)n_in; (void)out_size; (void)ws_size;
  const float* x = (const float*)d_in[0];      // [4,4096,512]
  const float* w_qkv = (const float*)d_in[1];  // [1536,512]
  const float* w_out = (const float*)d_in[2];  // [512,512]
  const float* b_out = (const float*)d_in[3];  // [512]
  float* out = (float*)d_out;                  // [4,4096,512] fp32

  unsigned short* ws0 = (unsigned short*)d_ws;
  unsigned short* wqkvb = ws0;              //   786,432
  unsigned short* woutb = ws0 + 786432;     //   262,144
  unsigned short* xb = ws0 + 1048576;       // 8,388,608
  unsigned short* Qb = ws0 + 9437184;       // 8,388,608
  unsigned short* Kb = ws0 + 17825792;      // 8,388,608
  unsigned short* Vb = ws0 + 26214400;      // 8,388,608
  unsigned short* AO = ws0 + 34603008;      // 8,388,608
  unsigned short* Zp = ws0 + 42991616;      // 64 shorts zero pad -> 86 MB

  cvt_all<<<4608, 256, 0, stream>>>(w_qkv, w_out, x, wqkvb, woutb, xb, Zp);
  gemm_qkv<<<1536, 256, 0, stream>>>(xb, wqkvb, Qb, Kb, Vb);
  attn_q4<<<2048, 256, 0, stream>>>(Qb, Kb, Vb, Zp, AO);
  gemm_out<<<512, 256, 0, stream>>>(AO, woutb, b_out, out);
}

// Round 12
// 171.136 us; speedup vs baseline: 1.1190x; 1.0141x over previous
//
#include <hip/hip_runtime.h>
#include <cstddef>
#include <cstdint>

// LocalAttention MI355X round 20 — consolidation to best-known config.
//   GEMM-core ledger (all A/B'd): 128^2 1-phase/5 blocks-per-CU BEST;
//   dbuf+syncthreads 53.5us; 256x128 46.4us; dbuf+counted-vmcnt +8us total.
//   Mechanism: short-K (8 steps) => TLP from 5 resident blocks beats any
//   intra-block pipeline that halves residency. GEMMs stay 1-phase 128^2.
//   attn_q4: async-DMA fill (r16) + fold 1/sum into PV epilogue (removes
//   the serial 25-mul pass before the V-wait; 16 muls in epilogue instead).
//   cvt_all unchanged.
// ws: 86 MB + 128 B of 256 MiB.

namespace {

typedef short s16x8 __attribute__((ext_vector_type(8)));
typedef unsigned short u16x8 __attribute__((ext_vector_type(8)));
typedef float f32x4 __attribute__((ext_vector_type(4)));

constexpr int kHeads = 8;
constexpr int kN = 4096;          // pixels per image
constexpr float kScale = 0.125f;  // 64^-0.5

__device__ inline float blo(unsigned u) {
  return __uint_as_float(u << 16);
}
__device__ inline float bhi(unsigned u) {
  return __uint_as_float(u & 0xffff0000u);
}
__device__ inline unsigned short f2b(float x) {
  unsigned u = __float_as_uint(x);  // RNE
  return (unsigned short)((u + 0x7fffu + ((u >> 16) & 1u)) >> 16);
}

// d += dot2(packed bf16 a, packed bf16 b), f32 accumulate (CDNA4 VOP3P)
__device__ __forceinline__ float dot2bf(float d, unsigned a, unsigned b) {
  asm("v_dot2_f32_bf16 %0, %1, %2, %0" : "+v"(d) : "v"(a), "v"(b));
  return d;
}

// async global->LDS, 16 B per lane; LDS dest = wave-uniform base + lane*16
__device__ __forceinline__ void g2l16(const unsigned short* g,
                                      unsigned short* l) {
  __builtin_amdgcn_global_load_lds(
      (const __attribute__((address_space(1))) void*)g,
      (__attribute__((address_space(3))) void*)l, 16, 0, 0);
}

// ---------------- fp32 -> bf16 for all three tensors -------------------------
__global__ __launch_bounds__(256) void cvt_all(
    const float* __restrict__ wq, const float* __restrict__ wo,
    const float* __restrict__ x, unsigned short* __restrict__ wqb,
    unsigned short* __restrict__ wob, unsigned short* __restrict__ xb,
    unsigned short* __restrict__ zp) {
  const int i = blockIdx.x * 256 + threadIdx.x;  // 0..1179647
  if (i < 16) ((unsigned long long*)zp)[i] = 0ull;  // 128B zero pad for attn
  const float* src;
  unsigned short* dst;
  int off;
  if (i < 98304) {
    src = wq; dst = wqb; off = i;
  } else if (i < 131072) {
    src = wo; dst = wob; off = i - 98304;
  } else {
    src = x; dst = xb; off = i - 131072;
  }
  const float4 a = ((const float4*)src)[off * 2];
  const float4 b = ((const float4*)src)[off * 2 + 1];
  u16x8 o;
  o[0] = f2b(a.x); o[1] = f2b(a.y); o[2] = f2b(a.z); o[3] = f2b(a.w);
  o[4] = f2b(b.x); o[5] = f2b(b.y); o[6] = f2b(b.z); o[7] = f2b(b.w);
  *(u16x8*)(dst + (size_t)off * 8) = o;
}

// ---------------- staging helper: one 128x64 half-K tile pair ---------------
__device__ __forceinline__ void stage64(const unsigned short* __restrict__ A,
                                        const unsigned short* __restrict__ W,
                                        int m0, int n0, int k0, int wv,
                                        int rsub, int slog,
                                        unsigned short* As,
                                        unsigned short* Bs) {
#pragma unroll
  for (int it = 0; it < 4; ++it) {
    const int g = wv * 4 + it;  // 0..15 -> 8-row group
    const int row = g * 8 + rsub;
    g2l16(A + (size_t)(m0 + row) * 512 + k0 + slog * 8, As + g * 512);
    g2l16(W + (size_t)(n0 + row) * 512 + k0 + slog * 8, Bs + g * 512);
  }
}

// ---------------- compute helper: 32 MFMA on one staged BK=64 tile ----------
__device__ __forceinline__ void compute64(const unsigned short* __restrict__ as,
                                          const unsigned short* __restrict__ bs,
                                          int lane, int wm, int wn,
                                          f32x4 (&acc)[4][4]) {
#pragma unroll
  for (int kh = 0; kh < 2; ++kh) {
    s16x8 af[4], bf[4];
    const int q = kh * 4 + (lane >> 4);  // logical k-seg wanted
#pragma unroll
    for (int i = 0; i < 4; ++i) {
      const int Ra = wm * 64 + i * 16 + (lane & 15);
      af[i] = *(const s16x8*)&as[Ra * 64 + ((q ^ (Ra & 7)) * 8)];
      const int Rb = wn * 64 + i * 16 + (lane & 15);
      bf[i] = *(const s16x8*)&bs[Rb * 64 + ((q ^ (Rb & 7)) * 8)];
    }
#pragma unroll
    for (int i = 0; i < 4; ++i)
#pragma unroll
      for (int j = 0; j < 4; ++j)
        acc[i][j] = __builtin_amdgcn_mfma_f32_16x16x32_bf16(
            af[i], bf[j], acc[i][j], 0, 0, 0);
  }
}

// ---------------- 1-phase MFMA core: 128x128 tile, K=512, BK=64 -------------
// 32 KB LDS -> 5 blocks/CU; TLP across blocks covers the stage latency
// (proven best vs dbuf/256-tile/counted-vmcnt variants, r17-r19).
__device__ __forceinline__ void mfma_512(const unsigned short* __restrict__ A,
                                         const unsigned short* __restrict__ W,
                                         int m0, int n0, int tid,
                                         unsigned short* As, unsigned short* Bs,
                                         f32x4 (&acc)[4][4]) {
  const int lane = tid & 63;
  const int wv = tid >> 6;
  const int wm = wv & 1, wn = wv >> 1;
  const int rsub = lane >> 3;
  const int slog = (lane & 7) ^ rsub;
#pragma unroll
  for (int i = 0; i < 4; ++i)
#pragma unroll
    for (int j = 0; j < 4; ++j) acc[i][j] = f32x4{0.f, 0.f, 0.f, 0.f};

  for (int k0 = 0; k0 < 512; k0 += 64) {
    stage64(A, W, m0, n0, k0, wv, rsub, slog, As, Bs);
    __syncthreads();
    compute64(As, Bs, lane, wm, wn, acc);
    __syncthreads();
  }
}

// ---------------- QKV projection GEMM, full M=16384 --------------------------
__global__ __launch_bounds__(256, 3) void gemm_qkv(
    const unsigned short* __restrict__ A, const unsigned short* __restrict__ W,
    unsigned short* __restrict__ Qb, unsigned short* __restrict__ Kb,
    unsigned short* __restrict__ Vb) {
  __shared__ unsigned short As[8192], Bs[8192];  // 16 KB each
  const int tid = threadIdx.x;
  const int id = blockIdx.x;
  const int xcd = id & 7;
  const int j = id >> 3;            // 0..191
  const int by = xcd * 16 + j / 12; // 0..127
  const int bx = j % 12;
  f32x4 acc[4][4];
  mfma_512(A, W, by * 128, bx * 128, tid, As, Bs, acc);

  const int lane = tid & 63;
  const int wv = tid >> 6;
  const int wm = wv & 1, wn = wv >> 1;
  const int cn = bx * 128 + wn * 64;  // 64-aligned => head/qkv wave-uniform
  unsigned short* dst = (cn < 512) ? Qb : (cn < 1024 ? Kb : Vb);
  const int head = (cn >> 6) & 7;
  const int colb = lane & 15;
#pragma unroll
  for (int mi = 0; mi < 4; ++mi) {
#pragma unroll
    for (int r = 0; r < 4; ++r) {
      const int m = by * 128 + wm * 64 + mi * 16 + (lane >> 4) * 4 + r;
      const int b = m >> 12;
      const int p = m & 4095;
      unsigned short* o =
          dst + ((size_t)(b * kHeads + head) * kN + p) * 64 + colb;
#pragma unroll
      for (int ni = 0; ni < 4; ++ni) o[ni * 16] = f2b(acc[mi][ni][r]);
    }
  }
}

// ---------------- out-projection GEMM ----------------------------------------
__global__ __launch_bounds__(256, 3) void gemm_out(
    const unsigned short* __restrict__ A, const unsigned short* __restrict__ W,
    const float* __restrict__ bias, float* __restrict__ out) {
  __shared__ unsigned short As[8192], Bs[8192];
  const int tid = threadIdx.x;
  const int id = blockIdx.x;
  const int xcd = id & 7;
  const int j = id >> 3;               // 0..63
  const int by = xcd * 16 + (j >> 2);  // 0..127
  const int bx = j & 3;
  f32x4 acc[4][4];
  mfma_512(A, W, by * 128, bx * 128, tid, As, Bs, acc);

  const int lane = tid & 63;
  const int wv = tid >> 6;
  const int wm = wv & 1, wn = wv >> 1;
  float bvr[4];
#pragma unroll
  for (int ni = 0; ni < 4; ++ni)
    bvr[ni] = bias[bx * 128 + wn * 64 + ni * 16 + (lane & 15)];
#pragma unroll
  for (int mi = 0; mi < 4; ++mi) {
#pragma unroll
    for (int r = 0; r < 4; ++r) {
      const int m = by * 128 + wm * 64 + mi * 16 + (lane >> 4) * 4 + r;
      float* o = out + (size_t)m * 512 + bx * 128 + wn * 64 + (lane & 15);
#pragma unroll
      for (int ni = 0; ni < 4; ++ni) o[ni * 16] = acc[mi][ni][r] + bvr[ni];
    }
  }
}

// ---------------- fused local attention, async-DMA fill ----------------------
// 256 threads/block, 8x8 pixel tile, quad-split (4 threads/pixel x 16 dims).
// H0 = K halo, H1 = V halo, 144 rows x 64 shorts each (36.86 KB total).
// Both fills are global_load_lds salvos issued at kernel start. Swizzle on
// the GLOBAL source (lane fetches chunk (lane&7)^(row&7)), LDS linear.
// OOB rows pull from a zeroed 128B ws slab. vmcnt(4): K drained, V in
// flight; QK + softmax overlap the V DMA; vmcnt(0)+barrier before PV.
// 1/sum folded into the PV epilogue (16 muls, no serial pass pre-barrier).
__global__ __launch_bounds__(256) void attn_q4(
    const unsigned short* __restrict__ Q, const unsigned short* __restrict__ K,
    const unsigned short* __restrict__ V, const unsigned short* __restrict__ Zp,
    unsigned short* __restrict__ AO) {
  __shared__ unsigned short H[2 * 144 * 64];  // 36.86 KB: [0]=K, [9216]=V
  const int tid = threadIdx.x;  // 0..255
  const int id = blockIdx.x;    // 0..2047
  const int wv = tid >> 6;
  // XCD-clustered mapping: 4 heads' K/V (2 MB) per XCD L2.
  const int xcd = id & 7;
  const int k8 = id >> 3;              // 0..255
  const int bh = xcd * 4 + (k8 >> 6);  // 0..31
  const int tile = k8 & 63;            // 0..63
  const int ty0 = (tile >> 3) * 8, tx0 = (tile & 7) * 8;
  const size_t base = (size_t)bh * kN;
  const int pix = tid >> 2;  // 0..63
  const int sub = tid & 3;   // which 16-dim quarter
  const int pyl = pix >> 3, pxl = pix & 7;
  const int p = (ty0 + pyl) * 64 + tx0 + pxl;

  // ---- prefetch Q (overlaps DMA issue) ----
  const unsigned short* qp = Q + (base + p) * 64 + sub * 16;
  const uint4 qa = *(const uint4*)qp;
  const uint4 qb = *(const uint4*)(qp + 8);

  // ---- issue K-halo DMA, then V-halo DMA (1152 16B chunks each) ----
#pragma unroll
  for (int it = 0; it < 5; ++it) {
    const int i = it * 256 + tid;
    if (i < 1152) {  // wave-uniform (wave chunk spans stay inside/outside)
      const int r = i >> 3;
      const int cg = (tid & 7) ^ (r & 7);  // pre-swizzled global chunk
      const int gy = ty0 - 2 + r / 12;
      const int gx = tx0 - 2 + r % 12;
      const unsigned short* src =
          ((unsigned)gy < 64u && (unsigned)gx < 64u)
              ? K + (base + (size_t)(gy * 64 + gx)) * 64 + cg * 8
              : Zp + cg * 8;
      g2l16(src, &H[(it * 32 + wv * 8) * 64]);
    }
  }
#pragma unroll
  for (int it = 0; it < 5; ++it) {
    const int i = it * 256 + tid;
    if (i < 1152) {
      const int r = i >> 3;
      const int cg = (tid & 7) ^ (r & 7);
      const int gy = ty0 - 2 + r / 12;
      const int gx = tx0 - 2 + r % 12;
      const unsigned short* src =
          ((unsigned)gy < 64u && (unsigned)gx < 64u)
              ? V + (base + (size_t)(gy * 64 + gx)) * 64 + cg * 8
              : Zp + cg * 8;
      g2l16(src, &H[9216 + (it * 32 + wv * 8) * 64]);
    }
  }

  // ---- wait K only (V stays in flight), all waves ----
  asm volatile("s_waitcnt vmcnt(4)" ::: "memory");
  __builtin_amdgcn_s_barrier();
  __builtin_amdgcn_sched_barrier(0);

  // ---- QK dots over own 16 dims, packed bf16 via v_dot2_f32_bf16 ----
  float dots[25];
#pragma unroll
  for (int fy = 0; fy < 5; ++fy) {
#pragma unroll
    for (int fx = 0; fx < 5; ++fx) {
      const int row = (pyl + fy) * 12 + pxl + fx;
      const int swz = (row & 7) << 3;  // shorts
      const unsigned short* hr = &H[row * 64];
      const uint4 ka = *(const uint4*)(hr + ((sub * 16) ^ swz));
      const uint4 kb = *(const uint4*)(hr + ((sub * 16 + 8) ^ swz));
      float d = 0.f;
      d = dot2bf(d, qa.x, ka.x);
      d = dot2bf(d, qa.y, ka.y);
      d = dot2bf(d, qa.z, ka.z);
      d = dot2bf(d, qa.w, ka.w);
      d = dot2bf(d, qb.x, kb.x);
      d = dot2bf(d, qb.y, kb.y);
      d = dot2bf(d, qb.z, kb.z);
      d = dot2bf(d, qb.w, kb.w);
      dots[fy * 5 + fx] = d;
    }
  }

  // ---- quad combine: lanes 4t..4t+3 are intra-wave ----
#pragma unroll
  for (int f = 0; f < 25; ++f) {
    dots[f] += __shfl_xor(dots[f], 1, 64);
    dots[f] += __shfl_xor(dots[f], 2, 64);
  }

  // ---- softmax (registers only; still overlapping V DMA) ----
  float mx = -1e30f;
#pragma unroll
  for (int f = 0; f < 25; ++f) {
    dots[f] *= kScale;
    mx = fmaxf(mx, dots[f]);
  }
  float sum = 0.f;
#pragma unroll
  for (int f = 0; f < 25; ++f) {
    dots[f] = __expf(dots[f] - mx);
    sum += dots[f];
  }
  const float inv = 1.f / sum;  // folded into PV epilogue

  // ---- V ready? drain DMA + barrier ----
  asm volatile("s_waitcnt vmcnt(0)" ::: "memory");
  __builtin_amdgcn_s_barrier();
  __builtin_amdgcn_sched_barrier(0);

  const int b = bh >> 3, h = bh & 7;
  unsigned short* op = AO + ((size_t)(b * kN + p)) * 512 + h * 64 + sub * 16;
#pragma unroll 1
  for (int hh = 0; hh < 2; ++hh) {  // two 8-dim passes (register pressure)
    float o[8];
#pragma unroll
    for (int j = 0; j < 8; ++j) o[j] = 0.f;
#pragma unroll
    for (int fy = 0; fy < 5; ++fy) {
#pragma unroll
      for (int fx = 0; fx < 5; ++fx) {
        const int row = (pyl + fy) * 12 + pxl + fx;
        const int swz = (row & 7) << 3;  // shorts
        const uint4 va =
            *(const uint4*)&H[9216 + row * 64 + ((sub * 16 + hh * 8) ^ swz)];
        const float wf = dots[fy * 5 + fx];
        o[0] = fmaf(wf, blo(va.x), o[0]);
        o[1] = fmaf(wf, bhi(va.x), o[1]);
        o[2] = fmaf(wf, blo(va.y), o[2]);
        o[3] = fmaf(wf, bhi(va.y), o[3]);
        o[4] = fmaf(wf, blo(va.z), o[4]);
        o[5] = fmaf(wf, bhi(va.z), o[5]);
        o[6] = fmaf(wf, blo(va.w), o[6]);
        o[7] = fmaf(wf, bhi(va.w), o[7]);
      }
    }
    u16x8 pk;
#pragma unroll
    for (int j = 0; j < 8; ++j) pk[j] = f2b(o[j] * inv);
    *(u16x8*)(op + hh * 8) = pk;
  }
}

}  // namespace

extern "C" void kernel_launch(void* const* d_in, const int* in_sizes, int n_in,
                              void* d_out, int out_size, void* d_ws,
                              size_t ws_size, hipStream_t stream) {
  (void)in_sizes; (void)n_in; (void)out_size; (void)ws_size;
  const float* x = (const float*)d_in[0];      // [4,4096,512]
  const float* w_qkv = (const float*)d_in[1];  // [1536,512]
  const float* w_out = (const float*)d_in[2];  // [512,512]
  const float* b_out = (const float*)d_in[3];  // [512]
  float* out = (float*)d_out;                  // [4,4096,512] fp32

  unsigned short* ws0 = (unsigned short*)d_ws;
  unsigned short* wqkvb = ws0;              //   786,432
  unsigned short* woutb = ws0 + 786432;     //   262,144
  unsigned short* xb = ws0 + 1048576;       // 8,388,608
  unsigned short* Qb = ws0 + 9437184;       // 8,388,608
  unsigned short* Kb = ws0 + 17825792;      // 8,388,608
  unsigned short* Vb = ws0 + 26214400;      // 8,388,608
  unsigned short* AO = ws0 + 34603008;      // 8,388,608
  unsigned short* Zp = ws0 + 42991616;      // 64 shorts zero pad -> 86 MB

  cvt_all<<<4608, 256, 0, stream>>>(w_qkv, w_out, x, wqkvb, woutb, xb, Zp);
  gemm_qkv<<<1536, 256, 0, stream>>>(xb, wqkvb, Qb, Kb, Vb);
  attn_q4<<<2048, 256, 0, stream>>>(Qb, Kb, Vb, Zp, AO);
  gemm_out<<<512, 256, 0, stream>>>(AO, woutb, b_out, out);
}

// Round 13
// 164.101 us; speedup vs baseline: 1.1670x; 1.0429x over previous
//
#include <hip/hip_runtime.h>
#include <cstddef>
#include <cstdint>

// LocalAttention MI355X round 21 — exact r16 restore (session best, 165.3 us).
//   r20's inv-fold (the only delta vs r16) paired with attn 54.5 us vs r8's
//   <41 — reverted. Ledger: r16=165.3 best; +counted-vmcnt=173.5;
//   +inv-fold=171.1; dbuf/256-tile GEMMs all worse. Mechanism notes:
//   short-K GEMM => 5-resident-block TLP beats any intra-block pipeline
//   costing LDS residency; attn critical path = LDS re-read (11x halo
//   amplification) with V-DMA hidden under QK+softmax.
//   cvt_all:   fp32 -> bf16 + 128B zero pad.
//   gemm_qkv/gemm_out: 1-phase 128^2 BK=64 MFMA core, (256,3), XOR-swizzled
//              global_load_lds staging, 32 KB LDS -> 5 blocks/CU.
//   attn_q4:   quad-split, async-DMA K->H0/V->H1 fill, pre-swizzled global
//              source, vmcnt(4) counted wait (K drained, V in flight),
//              QK+softmax overlap V DMA, vmcnt(0)+barrier, PV.
// ws: 86 MB + 128 B of 256 MiB.

namespace {

typedef short s16x8 __attribute__((ext_vector_type(8)));
typedef unsigned short u16x8 __attribute__((ext_vector_type(8)));
typedef float f32x4 __attribute__((ext_vector_type(4)));

constexpr int kHeads = 8;
constexpr int kN = 4096;          // pixels per image
constexpr float kScale = 0.125f;  // 64^-0.5

__device__ inline float blo(unsigned u) {
  return __uint_as_float(u << 16);
}
__device__ inline float bhi(unsigned u) {
  return __uint_as_float(u & 0xffff0000u);
}
__device__ inline unsigned short f2b(float x) {
  unsigned u = __float_as_uint(x);  // RNE
  return (unsigned short)((u + 0x7fffu + ((u >> 16) & 1u)) >> 16);
}

// d += dot2(packed bf16 a, packed bf16 b), f32 accumulate (CDNA4 VOP3P)
__device__ __forceinline__ float dot2bf(float d, unsigned a, unsigned b) {
  asm("v_dot2_f32_bf16 %0, %1, %2, %0" : "+v"(d) : "v"(a), "v"(b));
  return d;
}

// async global->LDS, 16 B per lane; LDS dest = wave-uniform base + lane*16
__device__ __forceinline__ void g2l16(const unsigned short* g,
                                      unsigned short* l) {
  __builtin_amdgcn_global_load_lds(
      (const __attribute__((address_space(1))) void*)g,
      (__attribute__((address_space(3))) void*)l, 16, 0, 0);
}

// ---------------- fp32 -> bf16 for all three tensors -------------------------
__global__ __launch_bounds__(256) void cvt_all(
    const float* __restrict__ wq, const float* __restrict__ wo,
    const float* __restrict__ x, unsigned short* __restrict__ wqb,
    unsigned short* __restrict__ wob, unsigned short* __restrict__ xb,
    unsigned short* __restrict__ zp) {
  const int i = blockIdx.x * 256 + threadIdx.x;  // 0..1179647
  if (i < 16) ((unsigned long long*)zp)[i] = 0ull;  // 128B zero pad for attn
  const float* src;
  unsigned short* dst;
  int off;
  if (i < 98304) {
    src = wq; dst = wqb; off = i;
  } else if (i < 131072) {
    src = wo; dst = wob; off = i - 98304;
  } else {
    src = x; dst = xb; off = i - 131072;
  }
  const float4 a = ((const float4*)src)[off * 2];
  const float4 b = ((const float4*)src)[off * 2 + 1];
  u16x8 o;
  o[0] = f2b(a.x); o[1] = f2b(a.y); o[2] = f2b(a.z); o[3] = f2b(a.w);
  o[4] = f2b(b.x); o[5] = f2b(b.y); o[6] = f2b(b.z); o[7] = f2b(b.w);
  *(u16x8*)(dst + (size_t)off * 8) = o;
}

// ---------------- MFMA GEMM core: 128x128 tile, K=512, BK=64 ----------------
// XOR-swizzled staging: lane stages logical k-seg (lane&7)^(row&7) so the
// g2l16-forced layout (base + lane*16B) yields bank-spread ds_read_b128.
__device__ __forceinline__ void mfma_512(const unsigned short* __restrict__ A,
                                         const unsigned short* __restrict__ W,
                                         int m0, int n0, int tid,
                                         unsigned short* As, unsigned short* Bs,
                                         f32x4 (&acc)[4][4]) {
  const int lane = tid & 63;
  const int wv = tid >> 6;
  const int wm = wv & 1, wn = wv >> 1;
  const int rsub = lane >> 3;              // row within 8-row group
  const int slog = (lane & 7) ^ rsub;      // logical k-seg this lane stages
#pragma unroll
  for (int i = 0; i < 4; ++i)
#pragma unroll
    for (int j = 0; j < 4; ++j) acc[i][j] = f32x4{0.f, 0.f, 0.f, 0.f};

  for (int k0 = 0; k0 < 512; k0 += 64) {
#pragma unroll
    for (int it = 0; it < 4; ++it) {
      const int g = wv * 4 + it;  // 0..15 -> 8-row group
      const int row = g * 8 + rsub;
      g2l16(A + (size_t)(m0 + row) * 512 + k0 + slog * 8, As + g * 512);
      g2l16(W + (size_t)(n0 + row) * 512 + k0 + slog * 8, Bs + g * 512);
    }
    __syncthreads();
#pragma unroll
    for (int kh = 0; kh < 2; ++kh) {
      s16x8 af[4], bf[4];
      const int q = kh * 4 + (lane >> 4);  // logical k-seg wanted
#pragma unroll
      for (int i = 0; i < 4; ++i) {
        const int Ra = wm * 64 + i * 16 + (lane & 15);
        af[i] = *(const s16x8*)&As[Ra * 64 + ((q ^ (Ra & 7)) * 8)];
        const int Rb = wn * 64 + i * 16 + (lane & 15);
        bf[i] = *(const s16x8*)&Bs[Rb * 64 + ((q ^ (Rb & 7)) * 8)];
      }
#pragma unroll
      for (int i = 0; i < 4; ++i)
#pragma unroll
        for (int j = 0; j < 4; ++j)
          acc[i][j] = __builtin_amdgcn_mfma_f32_16x16x32_bf16(
              af[i], bf[j], acc[i][j], 0, 0, 0);
    }
    __syncthreads();
  }
}

// ---------------- QKV projection GEMM, full M=16384 --------------------------
__global__ __launch_bounds__(256, 3) void gemm_qkv(
    const unsigned short* __restrict__ A, const unsigned short* __restrict__ W,
    unsigned short* __restrict__ Qb, unsigned short* __restrict__ Kb,
    unsigned short* __restrict__ Vb) {
  __shared__ unsigned short As[8192], Bs[8192];  // 16 KB each
  const int tid = threadIdx.x;
  const int id = blockIdx.x;
  const int xcd = id & 7;
  const int j = id >> 3;            // 0..191
  const int by = xcd * 16 + j / 12; // 0..127
  const int bx = j % 12;
  f32x4 acc[4][4];
  mfma_512(A, W, by * 128, bx * 128, tid, As, Bs, acc);

  const int lane = tid & 63;
  const int wv = tid >> 6;
  const int wm = wv & 1, wn = wv >> 1;
  const int cn = bx * 128 + wn * 64;  // 64-aligned => head/qkv wave-uniform
  unsigned short* dst = (cn < 512) ? Qb : (cn < 1024 ? Kb : Vb);
  const int head = (cn >> 6) & 7;
  const int colb = lane & 15;
#pragma unroll
  for (int mi = 0; mi < 4; ++mi) {
#pragma unroll
    for (int r = 0; r < 4; ++r) {
      const int m = by * 128 + wm * 64 + mi * 16 + (lane >> 4) * 4 + r;
      const int b = m >> 12;
      const int p = m & 4095;
      unsigned short* o =
          dst + ((size_t)(b * kHeads + head) * kN + p) * 64 + colb;
#pragma unroll
      for (int ni = 0; ni < 4; ++ni) o[ni * 16] = f2b(acc[mi][ni][r]);
    }
  }
}

// ---------------- out-projection GEMM ----------------------------------------
__global__ __launch_bounds__(256, 3) void gemm_out(
    const unsigned short* __restrict__ A, const unsigned short* __restrict__ W,
    const float* __restrict__ bias, float* __restrict__ out) {
  __shared__ unsigned short As[8192], Bs[8192];
  const int tid = threadIdx.x;
  const int id = blockIdx.x;
  const int xcd = id & 7;
  const int j = id >> 3;               // 0..63
  const int by = xcd * 16 + (j >> 2);  // 0..127
  const int bx = j & 3;
  f32x4 acc[4][4];
  mfma_512(A, W, by * 128, bx * 128, tid, As, Bs, acc);

  const int lane = tid & 63;
  const int wv = tid >> 6;
  const int wm = wv & 1, wn = wv >> 1;
  float bvr[4];
#pragma unroll
  for (int ni = 0; ni < 4; ++ni)
    bvr[ni] = bias[bx * 128 + wn * 64 + ni * 16 + (lane & 15)];
#pragma unroll
  for (int mi = 0; mi < 4; ++mi) {
#pragma unroll
    for (int r = 0; r < 4; ++r) {
      const int m = by * 128 + wm * 64 + mi * 16 + (lane >> 4) * 4 + r;
      float* o = out + (size_t)m * 512 + bx * 128 + wn * 64 + (lane & 15);
#pragma unroll
      for (int ni = 0; ni < 4; ++ni) o[ni * 16] = acc[mi][ni][r] + bvr[ni];
    }
  }
}

// ---------------- fused local attention, async-DMA fill ----------------------
// 256 threads/block, 8x8 pixel tile, quad-split (4 threads/pixel x 16 dims).
// H0 = K halo, H1 = V halo, 144 rows x 64 shorts each (36.86 KB total).
// Both fills are global_load_lds salvos issued at kernel start. Swizzle on
// the GLOBAL source (lane fetches chunk (lane&7)^(row&7)), LDS linear.
// OOB rows pull from a zeroed 128B ws slab. vmcnt(4): K drained, V in
// flight; QK + softmax overlap the V DMA; vmcnt(0)+barrier before PV.
__global__ __launch_bounds__(256) void attn_q4(
    const unsigned short* __restrict__ Q, const unsigned short* __restrict__ K,
    const unsigned short* __restrict__ V, const unsigned short* __restrict__ Zp,
    unsigned short* __restrict__ AO) {
  __shared__ unsigned short H[2 * 144 * 64];  // 36.86 KB: [0]=K, [9216]=V
  const int tid = threadIdx.x;  // 0..255
  const int id = blockIdx.x;    // 0..2047
  const int wv = tid >> 6;
  // XCD-clustered mapping: 4 heads' K/V (2 MB) per XCD L2.
  const int xcd = id & 7;
  const int k8 = id >> 3;              // 0..255
  const int bh = xcd * 4 + (k8 >> 6);  // 0..31
  const int tile = k8 & 63;            // 0..63
  const int ty0 = (tile >> 3) * 8, tx0 = (tile & 7) * 8;
  const size_t base = (size_t)bh * kN;
  const int pix = tid >> 2;  // 0..63
  const int sub = tid & 3;   // which 16-dim quarter
  const int pyl = pix >> 3, pxl = pix & 7;
  const int p = (ty0 + pyl) * 64 + tx0 + pxl;

  // ---- prefetch Q (overlaps DMA issue) ----
  const unsigned short* qp = Q + (base + p) * 64 + sub * 16;
  const uint4 qa = *(const uint4*)qp;
  const uint4 qb = *(const uint4*)(qp + 8);

  // ---- issue K-halo DMA, then V-halo DMA (1152 16B chunks each) ----
#pragma unroll
  for (int it = 0; it < 5; ++it) {
    const int i = it * 256 + tid;
    if (i < 1152) {  // wave-uniform (wave chunk spans stay inside/outside)
      const int r = i >> 3;
      const int cg = (tid & 7) ^ (r & 7);  // pre-swizzled global chunk
      const int gy = ty0 - 2 + r / 12;
      const int gx = tx0 - 2 + r % 12;
      const unsigned short* src =
          ((unsigned)gy < 64u && (unsigned)gx < 64u)
              ? K + (base + (size_t)(gy * 64 + gx)) * 64 + cg * 8
              : Zp + cg * 8;
      g2l16(src, &H[(it * 32 + wv * 8) * 64]);
    }
  }
#pragma unroll
  for (int it = 0; it < 5; ++it) {
    const int i = it * 256 + tid;
    if (i < 1152) {
      const int r = i >> 3;
      const int cg = (tid & 7) ^ (r & 7);
      const int gy = ty0 - 2 + r / 12;
      const int gx = tx0 - 2 + r % 12;
      const unsigned short* src =
          ((unsigned)gy < 64u && (unsigned)gx < 64u)
              ? V + (base + (size_t)(gy * 64 + gx)) * 64 + cg * 8
              : Zp + cg * 8;
      g2l16(src, &H[9216 + (it * 32 + wv * 8) * 64]);
    }
  }

  // ---- wait K only (V stays in flight), all waves ----
  asm volatile("s_waitcnt vmcnt(4)" ::: "memory");
  __builtin_amdgcn_s_barrier();
  __builtin_amdgcn_sched_barrier(0);

  // ---- QK dots over own 16 dims, packed bf16 via v_dot2_f32_bf16 ----
  float dots[25];
#pragma unroll
  for (int fy = 0; fy < 5; ++fy) {
#pragma unroll
    for (int fx = 0; fx < 5; ++fx) {
      const int row = (pyl + fy) * 12 + pxl + fx;
      const int swz = (row & 7) << 3;  // shorts
      const unsigned short* hr = &H[row * 64];
      const uint4 ka = *(const uint4*)(hr + ((sub * 16) ^ swz));
      const uint4 kb = *(const uint4*)(hr + ((sub * 16 + 8) ^ swz));
      float d = 0.f;
      d = dot2bf(d, qa.x, ka.x);
      d = dot2bf(d, qa.y, ka.y);
      d = dot2bf(d, qa.z, ka.z);
      d = dot2bf(d, qa.w, ka.w);
      d = dot2bf(d, qb.x, kb.x);
      d = dot2bf(d, qb.y, kb.y);
      d = dot2bf(d, qb.z, kb.z);
      d = dot2bf(d, qb.w, kb.w);
      dots[fy * 5 + fx] = d;
    }
  }

  // ---- quad combine: lanes 4t..4t+3 are intra-wave ----
#pragma unroll
  for (int f = 0; f < 25; ++f) {
    dots[f] += __shfl_xor(dots[f], 1, 64);
    dots[f] += __shfl_xor(dots[f], 2, 64);
  }

  // ---- softmax (registers only; still overlapping V DMA) ----
  float mx = -1e30f;
#pragma unroll
  for (int f = 0; f < 25; ++f) {
    dots[f] *= kScale;
    mx = fmaxf(mx, dots[f]);
  }
  float sum = 0.f;
#pragma unroll
  for (int f = 0; f < 25; ++f) {
    dots[f] = __expf(dots[f] - mx);
    sum += dots[f];
  }
  const float inv = 1.f / sum;
#pragma unroll
  for (int f = 0; f < 25; ++f) dots[f] *= inv;

  // ---- V ready? drain DMA + barrier ----
  asm volatile("s_waitcnt vmcnt(0)" ::: "memory");
  __builtin_amdgcn_s_barrier();
  __builtin_amdgcn_sched_barrier(0);

  const int b = bh >> 3, h = bh & 7;
  unsigned short* op = AO + ((size_t)(b * kN + p)) * 512 + h * 64 + sub * 16;
#pragma unroll 1
  for (int hh = 0; hh < 2; ++hh) {  // two 8-dim passes (register pressure)
    float o[8];
#pragma unroll
    for (int j = 0; j < 8; ++j) o[j] = 0.f;
#pragma unroll
    for (int fy = 0; fy < 5; ++fy) {
#pragma unroll
      for (int fx = 0; fx < 5; ++fx) {
        const int row = (pyl + fy) * 12 + pxl + fx;
        const int swz = (row & 7) << 3;  // shorts
        const uint4 va =
            *(const uint4*)&H[9216 + row * 64 + ((sub * 16 + hh * 8) ^ swz)];
        const float wf = dots[fy * 5 + fx];
        o[0] = fmaf(wf, blo(va.x), o[0]);
        o[1] = fmaf(wf, bhi(va.x), o[1]);
        o[2] = fmaf(wf, blo(va.y), o[2]);
        o[3] = fmaf(wf, bhi(va.y), o[3]);
        o[4] = fmaf(wf, blo(va.z), o[4]);
        o[5] = fmaf(wf, bhi(va.z), o[5]);
        o[6] = fmaf(wf, blo(va.w), o[6]);
        o[7] = fmaf(wf, bhi(va.w), o[7]);
      }
    }
    u16x8 pk;
#pragma unroll
    for (int j = 0; j < 8; ++j) pk[j] = f2b(o[j]);
    *(u16x8*)(op + hh * 8) = pk;
  }
}

}  // namespace

extern "C" void kernel_launch(void* const* d_in, const int* in_sizes, int n_in,
                              void* d_out, int out_size, void* d_ws,
                              size_t ws_size, hipStream_t stream) {
  (void)in_sizes; (void)n_in; (void)out_size; (void)ws_size;
  const float* x = (const float*)d_in[0];      // [4,4096,512]
  const float* w_qkv = (const float*)d_in[1];  // [1536,512]
  const float* w_out = (const float*)d_in[2];  // [512,512]
  const float* b_out = (const float*)d_in[3];  // [512]
  float* out = (float*)d_out;                  // [4,4096,512] fp32

  unsigned short* ws0 = (unsigned short*)d_ws;
  unsigned short* wqkvb = ws0;              //   786,432
  unsigned short* woutb = ws0 + 786432;     //   262,144
  unsigned short* xb = ws0 + 1048576;       // 8,388,608
  unsigned short* Qb = ws0 + 9437184;       // 8,388,608
  unsigned short* Kb = ws0 + 17825792;      // 8,388,608
  unsigned short* Vb = ws0 + 26214400;      // 8,388,608
  unsigned short* AO = ws0 + 34603008;      // 8,388,608
  unsigned short* Zp = ws0 + 42991616;      // 64 shorts zero pad -> 86 MB

  cvt_all<<<4608, 256, 0, stream>>>(w_qkv, w_out, x, wqkvb, woutb, xb, Zp);
  gemm_qkv<<<1536, 256, 0, stream>>>(xb, wqkvb, Qb, Kb, Vb);
  attn_q4<<<2048, 256, 0, stream>>>(Qb, Kb, Vb, Zp, AO);
  gemm_out<<<512, 256, 0, stream>>>(AO, woutb, b_out, out);
}